// Round 2
// baseline (3129.181 us; speedup 1.0000x reference)
//
#include <hip/hip_runtime.h>

#define DM    2048
#define DFF   8192
#define NH    16
#define DKH   128
#define BB    128
#define SS    128
#define MROWS (BB*SS)   // 16384

typedef __bf16 bf16;
using bf16x8v = __attribute__((ext_vector_type(8))) __bf16;
using bf16x4v = __attribute__((ext_vector_type(4))) __bf16;
using f32x4   = __attribute__((ext_vector_type(4))) float;

__device__ __forceinline__ f32x4 mfma16(bf16x8v a, bf16x8v b, f32x4 c) {
  return __builtin_amdgcn_mfma_f32_16x16x32_bf16(a, b, c, 0, 0, 0);
}

__device__ __forceinline__ void async16(const void* g, void* l) {
  __builtin_amdgcn_global_load_lds(
      (const __attribute__((address_space(1))) void*)g,
      (__attribute__((address_space(3))) void*)l, 16, 0, 0);
}

// ---------------------------------------------------------------- casts
__global__ __launch_bounds__(256) void cast_bf16_kernel(const float* __restrict__ in,
                                                        bf16* __restrict__ out) {
  size_t i = ((size_t)blockIdx.x * 256 + threadIdx.x) * 4;
  float4 v = *(const float4*)(in + i);
  bf16x4v o = { (bf16)v.x, (bf16)v.y, (bf16)v.z, (bf16)v.w };
  *(bf16x4v*)(out + i) = o;
}

// in: fp32 [R][C]  ->  out: bf16 [C][R]
__global__ __launch_bounds__(256) void transpose_cast_kernel(const float* __restrict__ in,
                                                             bf16* __restrict__ out,
                                                             int R, int C) {
  __shared__ float tile[32][33];
  int c0 = blockIdx.x * 32, r0 = blockIdx.y * 32;
  int tx = threadIdx.x & 31;
  int ty = threadIdx.x >> 5;  // 0..7
  #pragma unroll
  for (int i = ty; i < 32; i += 8)
    tile[i][tx] = in[(size_t)(r0 + i) * C + c0 + tx];
  __syncthreads();
  #pragma unroll
  for (int i = ty; i < 32; i += 8)
    out[(size_t)(c0 + i) * R + r0 + tx] = (bf16)tile[tx][i];
}

// ---------------------------------------------------------------- GEMM (m97 structure)
// out[M][N] = A[M][K] @ Bt[N][K]^T + bias (+ resid), epilogue optional GELU.
// Writes bf16 (Cb) or fp32 (Cf) — exactly one of Cb/Cf is non-null.
#define BM 128
#define BN 128
#define BK 32

__global__ __launch_bounds__(256) void gemm_bt_kernel(
    const bf16* __restrict__ A, const bf16* __restrict__ Bt,
    const float* __restrict__ bias, const bf16* __restrict__ resid,
    bf16* __restrict__ Cb, float* __restrict__ Cf,
    int M, int N, int K, int do_gelu)
{
  __shared__ __align__(16) bf16 As[BM * BK];  // [m][k], unpadded (global_load_lds contiguity)
  __shared__ __align__(16) bf16 Bs[BN * BK];  // [n][k]
  const int tid  = threadIdx.x;
  const int lane = tid & 63;
  const int wave = tid >> 6;
  const int wm = (wave >> 1) * 64;
  const int wn = (wave & 1) * 64;
  const int lr = lane & 15;
  const int lk = (lane >> 4) * 8;
  const int bm = blockIdx.y, bn = blockIdx.x;

  const int sr   = tid >> 2;         // staging row 0..63
  const int scol = (tid & 3) * 8;    // staging col 0,8,16,24
  const bf16* Ag = A  + (size_t)(bm * BM + sr) * K + scol;
  const bf16* Bg = Bt + (size_t)(bn * BN + sr) * K + scol;
  bf16* As_l = As + tid * 8;         // lds byte off = tid*16 = wave base + lane*16
  bf16* Bs_l = Bs + tid * 8;

  f32x4 acc[4][4];
  #pragma unroll
  for (int i = 0; i < 4; i++)
    #pragma unroll
    for (int j = 0; j < 4; j++) acc[i][j] = (f32x4){0.f, 0.f, 0.f, 0.f};

  for (int k0 = 0; k0 < K; k0 += BK) {
    __syncthreads();                       // frag reads of prev iter done
    async16(Ag + k0,                 As_l);
    async16(Ag + (size_t)64*K + k0,  As_l + 2048);
    async16(Bg + k0,                 Bs_l);
    async16(Bg + (size_t)64*K + k0,  Bs_l + 2048);
    __syncthreads();                       // vmcnt(0) drain -> LDS valid
    bf16x8v af[4], bfr[4];
    #pragma unroll
    for (int t = 0; t < 4; t++)
      af[t] = *(const bf16x8v*)(As + (wm + t*16 + lr) * BK + lk);
    #pragma unroll
    for (int t = 0; t < 4; t++)
      bfr[t] = *(const bf16x8v*)(Bs + (wn + t*16 + lr) * BK + lk);
    #pragma unroll
    for (int i = 0; i < 4; i++)
      #pragma unroll
      for (int j = 0; j < 4; j++)
        acc[i][j] = mfma16(af[i], bfr[j], acc[i][j]);
  }

  const int row0 = bm * BM + wm + (lane >> 4) * 4;
  const int col0 = bn * BN + wn + lr;
  #pragma unroll
  for (int j = 0; j < 4; j++) {
    const int col = col0 + j * 16;
    const float bv = bias[col];
    #pragma unroll
    for (int i = 0; i < 4; i++) {
      #pragma unroll
      for (int r = 0; r < 4; r++) {
        const int row = row0 + i * 16 + r;
        float v = acc[i][j][r] + bv;
        if (do_gelu) v = 0.5f * v * (1.0f + erff(v * 0.70710678118654752f));
        if (resid)   v += (float)resid[(size_t)row * N + col];
        if (Cf) Cf[(size_t)row * N + col] = v;
        else    Cb[(size_t)row * N + col] = (bf16)v;
      }
    }
  }
}

// ---------------------------------------------------------------- attention
// one block (256 thr, 4 waves) per (b,h).  scores[b,h,i,j] =
//   (Q.K^T)/sqrt(128) + rel_emb[(b-i) mod 512][j]  (reference broadcast quirk)
#define SMS 136  // padded LDS stride: 272 B = 17*16 -> b128-aligned, 2-way banks (free)

__global__ __launch_bounds__(256) void attn_kernel(
    const bf16* __restrict__ Q, const bf16* __restrict__ K,
    const bf16* __restrict__ V, const float* __restrict__ rel,
    bf16* __restrict__ ctx)
{
  __shared__ __align__(16) bf16 smem[192 * SMS];      // 52224 B
  bf16* Ks = smem;                                    // [128][SMS] phase 1
  bf16* Ps = smem;                                    // [128][SMS] phase 2 (aliases Ks)
  bf16* VT = smem + 128 * SMS;                        // [64][SMS]  phase 2

  const int tid  = threadIdx.x;
  const int lane = tid & 63, wave = tid >> 6;
  const int lr = lane & 15, lq = lane >> 4, lk = lq * 8;
  const int bh = blockIdx.x;
  const int b = bh >> 4, h = bh & 15;
  const size_t base = (size_t)b * SS * DM + (size_t)h * DKH;

  // stage K [j][d]
  #pragma unroll
  for (int p = 0; p < 8; p++) {
    int idx = p * 256 + tid;
    int row = idx >> 4;
    int col = (idx & 15) * 8;
    *(int4*)(Ks + row * SMS + col) = *(const int4*)(K + base + (size_t)row * DM + col);
  }
  // Q fragments straight from global
  bf16x8v qf[2][4];
  #pragma unroll
  for (int mt = 0; mt < 2; mt++)
    #pragma unroll
    for (int ks = 0; ks < 4; ks++)
      qf[mt][ks] = *(const bf16x8v*)(Q + base + (size_t)(wave*32 + mt*16 + lr) * DM + ks*32 + lk);

  __syncthreads();

  f32x4 sc[2][8];
  #pragma unroll
  for (int mt = 0; mt < 2; mt++)
    #pragma unroll
    for (int nt = 0; nt < 8; nt++) sc[mt][nt] = (f32x4){0.f, 0.f, 0.f, 0.f};

  #pragma unroll
  for (int ks = 0; ks < 4; ks++) {
    #pragma unroll
    for (int nt = 0; nt < 8; nt++) {
      bf16x8v kf = *(const bf16x8v*)(Ks + (nt*16 + lr) * SMS + ks*32 + lk);
      sc[0][nt] = mfma16(qf[0][ks], kf, sc[0][nt]);
      sc[1][nt] = mfma16(qf[1][ks], kf, sc[1][nt]);
    }
  }
  __syncthreads();   // all waves done reading Ks; Ps region may be overwritten

  const float scale = 0.08838834764831845f;  // 1/sqrt(128)
  #pragma unroll
  for (int mt = 0; mt < 2; mt++) {
    #pragma unroll
    for (int r = 0; r < 4; r++) {
      int i = wave * 32 + mt * 16 + lq * 4 + r;
      int dmi = b - i; if (dmi < 0) dmi += 512;
      const float* relrow = rel + (size_t)dmi * DKH + lr;
      float vv[8];
      float mx = -1e30f;
      #pragma unroll
      for (int nt = 0; nt < 8; nt++) {
        float v = sc[mt][nt][r] * scale + relrow[nt * 16];
        vv[nt] = v;
        mx = fmaxf(mx, v);
      }
      #pragma unroll
      for (int m = 1; m < 16; m <<= 1) mx = fmaxf(mx, __shfl_xor(mx, m));
      float sum = 0.f;
      #pragma unroll
      for (int nt = 0; nt < 8; nt++) { vv[nt] = __expf(vv[nt] - mx); sum += vv[nt]; }
      #pragma unroll
      for (int m = 1; m < 16; m <<= 1) sum += __shfl_xor(sum, m);
      float inv = 1.f / sum;
      #pragma unroll
      for (int nt = 0; nt < 8; nt++)
        Ps[i * SMS + nt * 16 + lr] = (bf16)(vv[nt] * inv);
    }
  }

  #pragma unroll
  for (int half = 0; half < 2; half++) {
    __syncthreads();                       // Ps written / prev VT reads done
    const int d0 = half * 64;
    #pragma unroll
    for (int p = 0; p < 4; p++) {
      int idx = p * 256 + tid;             // 128 j x 8 chunks
      int j  = idx >> 3;
      int dc = (idx & 7) * 8;
      union { int4 i4; bf16 hh[8]; } u;
      u.i4 = *(const int4*)(V + base + (size_t)j * DM + d0 + dc);
      #pragma unroll
      for (int uu = 0; uu < 8; uu++)
        VT[(dc + uu) * SMS + j] = u.hh[uu];
    }
    __syncthreads();
    f32x4 oa[2][4];
    #pragma unroll
    for (int mt = 0; mt < 2; mt++)
      #pragma unroll
      for (int nt = 0; nt < 4; nt++) oa[mt][nt] = (f32x4){0.f, 0.f, 0.f, 0.f};
    #pragma unroll
    for (int ks = 0; ks < 4; ks++) {
      bf16x8v pf0 = *(const bf16x8v*)(Ps + (wave*32 +      lr) * SMS + ks*32 + lk);
      bf16x8v pf1 = *(const bf16x8v*)(Ps + (wave*32 + 16 + lr) * SMS + ks*32 + lk);
      #pragma unroll
      for (int nt = 0; nt < 4; nt++) {
        bf16x8v vf = *(const bf16x8v*)(VT + (nt*16 + lr) * SMS + ks*32 + lk);
        oa[0][nt] = mfma16(pf0, vf, oa[0][nt]);
        oa[1][nt] = mfma16(pf1, vf, oa[1][nt]);
      }
    }
    #pragma unroll
    for (int mt = 0; mt < 2; mt++)
      #pragma unroll
      for (int nt = 0; nt < 4; nt++)
        #pragma unroll
        for (int r = 0; r < 4; r++) {
          int i = wave * 32 + mt * 16 + lq * 4 + r;
          int d = d0 + nt * 16 + lr;
          ctx[base + (size_t)i * DM + d] = (bf16)oa[mt][nt][r];
        }
  }
}

// ---------------------------------------------------------------- LN kernels
// x1 = LN(xf + yb)*g + be  -> bf16
__global__ __launch_bounds__(256) void resid_ln1_kernel(
    const float* __restrict__ xf, const bf16* __restrict__ yb,
    const float* __restrict__ g, const float* __restrict__ be,
    bf16* __restrict__ outb)
{
  const int row = blockIdx.x;
  const int tid = threadIdx.x;
  const size_t off = (size_t)row * DM + tid * 8;
  float v[8];
  {
    float4 a = *(const float4*)(xf + off);
    float4 c = *(const float4*)(xf + off + 4);
    v[0]=a.x; v[1]=a.y; v[2]=a.z; v[3]=a.w;
    v[4]=c.x; v[5]=c.y; v[6]=c.z; v[7]=c.w;
    union { int4 i4; bf16 hh[8]; } u;
    u.i4 = *(const int4*)(yb + off);
    #pragma unroll
    for (int t = 0; t < 8; t++) v[t] += (float)u.hh[t];
  }
  float s1 = 0.f, s2 = 0.f;
  #pragma unroll
  for (int t = 0; t < 8; t++) { s1 += v[t]; s2 += v[t] * v[t]; }
  #pragma unroll
  for (int m = 1; m < 64; m <<= 1) { s1 += __shfl_xor(s1, m); s2 += __shfl_xor(s2, m); }
  __shared__ float r1[4], r2[4];
  if ((tid & 63) == 0) { r1[tid >> 6] = s1; r2[tid >> 6] = s2; }
  __syncthreads();
  s1 = r1[0] + r1[1] + r1[2] + r1[3];
  s2 = r2[0] + r2[1] + r2[2] + r2[3];
  const float mu  = s1 * (1.f / DM);
  const float var = s2 * (1.f / DM) - mu * mu;
  const float rstd = rsqrtf(var + 1e-5f);
  const int c0 = tid * 8;
  union { int4 i4; bf16 hh[8]; } w;
  #pragma unroll
  for (int t = 0; t < 8; t++)
    w.hh[t] = (bf16)((v[t] - mu) * rstd * g[c0 + t] + be[c0 + t]);
  *(int4*)(outb + off) = w.i4;
}

// out = LN(in)*g + be, in fp32 split across two half buffers, out fp32
__global__ __launch_bounds__(256) void ln_final_kernel(
    const float* __restrict__ f0, const float* __restrict__ f1,
    const float* __restrict__ g, const float* __restrict__ be,
    float* __restrict__ out)
{
  const int row = blockIdx.x;
  const int tid = threadIdx.x;
  const float* src = (row < MROWS/2) ? (f0 + (size_t)row * DM)
                                     : (f1 + (size_t)(row - MROWS/2) * DM);
  const size_t off = (size_t)tid * 8;
  float v[8];
  {
    float4 a = *(const float4*)(src + off);
    float4 c = *(const float4*)(src + off + 4);
    v[0]=a.x; v[1]=a.y; v[2]=a.z; v[3]=a.w;
    v[4]=c.x; v[5]=c.y; v[6]=c.z; v[7]=c.w;
  }
  float s1 = 0.f, s2 = 0.f;
  #pragma unroll
  for (int t = 0; t < 8; t++) { s1 += v[t]; s2 += v[t] * v[t]; }
  #pragma unroll
  for (int m = 1; m < 64; m <<= 1) { s1 += __shfl_xor(s1, m); s2 += __shfl_xor(s2, m); }
  __shared__ float r1[4], r2[4];
  if ((tid & 63) == 0) { r1[tid >> 6] = s1; r2[tid >> 6] = s2; }
  __syncthreads();
  s1 = r1[0] + r1[1] + r1[2] + r1[3];
  s2 = r2[0] + r2[1] + r2[2] + r2[3];
  const float mu  = s1 * (1.f / DM);
  const float var = s2 * (1.f / DM) - mu * mu;
  const float rstd = rsqrtf(var + 1e-5f);
  const int c0 = tid * 8;
  float o[8];
  #pragma unroll
  for (int t = 0; t < 8; t++) o[t] = (v[t] - mu) * rstd * g[c0 + t] + be[c0 + t];
  float4 o0 = {o[0],o[1],o[2],o[3]};
  float4 o1 = {o[4],o[5],o[6],o[7]};
  float* dst = out + (size_t)row * DM + tid * 8;
  *(float4*)(dst) = o0;
  *(float4*)(dst + 4) = o1;
}

// ---------------------------------------------------------------- launch
// Workspace budget: 3*NE bf16 slots (201 MB) + W1T+W2T (67 MB) = 268 MB.
// d_out (128 MiB) doubles as scratch: Q/K (phase 1) then FFN h-half (phase 3).
extern "C" void kernel_launch(void* const* d_in, const int* in_sizes, int n_in,
                              void* d_out, int out_size, void* d_ws, size_t ws_size,
                              hipStream_t stream) {
  const float* x    = (const float*)d_in[0];
  const float* Wq   = (const float*)d_in[1];
  const float* bq   = (const float*)d_in[2];
  const float* Wk   = (const float*)d_in[3];
  const float* bk   = (const float*)d_in[4];
  const float* Wv   = (const float*)d_in[5];
  const float* bv   = (const float*)d_in[6];
  const float* Wo   = (const float*)d_in[7];
  const float* bo   = (const float*)d_in[8];
  const float* rel  = (const float*)d_in[9];
  const float* g1   = (const float*)d_in[10];
  const float* be1  = (const float*)d_in[11];
  const float* W1   = (const float*)d_in[12];
  const float* b1   = (const float*)d_in[13];
  const float* W2   = (const float*)d_in[14];
  const float* b2   = (const float*)d_in[15];
  const float* g2   = (const float*)d_in[16];
  const float* be2  = (const float*)d_in[17];

  const size_t NE = (size_t)MROWS * DM;  // 33,554,432
  bf16* ws  = (bf16*)d_ws;
  bf16* p0  = ws;                         // Q -> attn-out -> f1(fp32)
  bf16* p1  = ws + NE;                    // V -> x1
  bf16* p2  = ws + 2 * NE;                // xb -> ctx -> f0(fp32)
  bf16* wT  = ws + 3 * NE;                // transposed weight A (up to DM*DFF)
  bf16* wT2 = wT + (size_t)DM * DFF;      // transposed weight B

  bf16* dQ = (bf16*)d_out;                // Q in d_out scratch
  bf16* dK = dQ + NE;                     // K in d_out scratch
  bf16* dH = (bf16*)d_out;                // FFN hidden half (8192 x 8192 bf16)
  float* f0 = (float*)p2;                 // ff+resid fp32, rows 0..8191
  float* f1 = (float*)p0;                 // ff+resid fp32, rows 8192..16383

  dim3 gq(DM / BN, MROWS / BM);           // (16, 128)
  dim3 gh(DFF / BN, (MROWS/2) / BM);      // (64, 64)  FFN1 half
  dim3 gh2(DM / BN, (MROWS/2) / BM);      // (16, 64)  FFN2 half

  // phase 1: cast + QKV projections (weights transposed just-in-time)
  cast_bf16_kernel<<<NE / 1024, 256, 0, stream>>>(x, p2);
  transpose_cast_kernel<<<dim3(DM/32, DM/32), 256, 0, stream>>>(Wq, wT, DM, DM);
  gemm_bt_kernel<<<gq, 256, 0, stream>>>(p2, wT, bq, nullptr, dQ, nullptr, MROWS, DM, DM, 0);
  transpose_cast_kernel<<<dim3(DM/32, DM/32), 256, 0, stream>>>(Wk, wT2, DM, DM);
  gemm_bt_kernel<<<gq, 256, 0, stream>>>(p2, wT2, bk, nullptr, dK, nullptr, MROWS, DM, DM, 0);
  transpose_cast_kernel<<<dim3(DM/32, DM/32), 256, 0, stream>>>(Wv, wT, DM, DM);
  gemm_bt_kernel<<<gq, 256, 0, stream>>>(p2, wT, bv, nullptr, p1, nullptr, MROWS, DM, DM, 0);

  // phase 2: attention + out-proj + LN1
  transpose_cast_kernel<<<dim3(DM/32, DM/32), 256, 0, stream>>>(Wo, wT2, DM, DM);
  attn_kernel<<<BB * NH, 256, 0, stream>>>(dQ, dK, p1, rel, p2);   // ctx -> p2 (xb dead)
  gemm_bt_kernel<<<gq, 256, 0, stream>>>(p2, wT2, bo, nullptr, p0, nullptr, MROWS, DM, DM, 0);
  resid_ln1_kernel<<<MROWS, 256, 0, stream>>>(x, p0, g1, be1, p1); // x1 -> p1 (V dead)

  // phase 3: FFN split into two M-halves; h lives in d_out (Q/K dead)
  transpose_cast_kernel<<<dim3(DFF/32, DM/32), 256, 0, stream>>>(W1, wT, DM, DFF);   // [DFF][DM]
  transpose_cast_kernel<<<dim3(DM/32, DFF/32), 256, 0, stream>>>(W2, wT2, DFF, DM);  // [DM][DFF]
  for (int half = 0; half < 2; half++) {
    const bf16* x1h = p1 + (size_t)half * (MROWS/2) * DM;
    float*      fo  = half ? f1 : f0;
    gemm_bt_kernel<<<gh, 256, 0, stream>>>(x1h, wT, b1, nullptr, dH, nullptr,
                                           MROWS/2, DFF, DM, 1);
    gemm_bt_kernel<<<gh2, 256, 0, stream>>>(dH, wT2, b2, x1h, nullptr, fo,
                                            MROWS/2, DM, DFF, 0);
  }
  ln_final_kernel<<<MROWS, 256, 0, stream>>>(f0, f1, g2, be2, (float*)d_out);
}